// Round 1
// baseline (1728.322 us; speedup 1.0000x reference)
//
#include <hip/hip_runtime.h>

#define P_ 128
#define T_ 2048
#define D_ 128
#define H_ 64
#define G_ 192
#define OUT_ 24

__device__ __forceinline__ float sigmoidf_(float x){ return 1.0f/(1.0f + __expf(-x)); }
__device__ __forceinline__ float tanhf_(float x){
  float a = fabsf(x);
  float e = __expf(-2.0f*a);
  float t = (1.0f - e)/(1.0f + e);
  return copysignf(t, x);
}

// ---------------- Phase 1: x_proj[p, tl, g] = sum_d z[p,t0+tl,d]*w_ih[p,g,d] + b_ih[p,g]
// Block: one part x 64-t tile. z tile staged in LDS; w_ih read from global (L1 broadcast).
__global__ __launch_bounds__(256) void xproj_kernel(
    const float* __restrict__ z, const float* __restrict__ w_ih,
    const float* __restrict__ b_ih, float* __restrict__ xp,
    int t0, int tcLen)
{
  __shared__ float zl[64*132];                  // 64 t-rows x 128 k, stride 132 (pad 4, 16B-aligned)
  const int p = blockIdx.y;
  const int tBase = blockIdx.x*64;              // local t within chunk
  const int tid = threadIdx.x;
  const float* zg = z + ((size_t)p*T_ + (size_t)(t0 + tBase))*D_;
  #pragma unroll
  for (int i=0;i<8;i++){
    int idx = tid + i*256;
    int r = idx >> 5, c = idx & 31;
    *(float4*)(zl + r*132 + c*4) = *(const float4*)(zg + (size_t)r*D_ + c*4);
  }
  __syncthreads();

  const int tg = tid & 15, ng = tid >> 4;       // t fast (broadcast-friendly W), ng in [0,16), NPT=12
  const int n0 = ng*12, tr = tg*4;
  const float* wg = w_ih + (size_t)p*G_*D_;
  float acc[4][12];
  #pragma unroll
  for (int j=0;j<12;j++){
    float b = b_ih[p*G_ + n0 + j];
    #pragma unroll
    for (int i=0;i<4;i++) acc[i][j] = b;
  }
  #pragma unroll 4
  for (int k=0;k<D_;k+=4){
    float4 x4[4];
    #pragma unroll
    for (int i=0;i<4;i++) x4[i] = *(const float4*)(zl + (tr+i)*132 + k);
    #pragma unroll
    for (int j=0;j<12;j++){
      float4 w4 = *(const float4*)(wg + (size_t)(n0+j)*D_ + k);
      #pragma unroll
      for (int i=0;i<4;i++)
        acc[i][j] = fmaf(x4[i].x,w4.x, fmaf(x4[i].y,w4.y, fmaf(x4[i].z,w4.z, fmaf(x4[i].w,w4.w, acc[i][j]))));
    }
  }
  float* orow = xp + ((size_t)p*tcLen + tBase)*G_;
  #pragma unroll
  for (int i=0;i<4;i++){
    #pragma unroll
    for (int j3=0;j3<3;j3++){
      float4 v = make_float4(acc[i][j3*4+0],acc[i][j3*4+1],acc[i][j3*4+2],acc[i][j3*4+3]);
      *(float4*)(orow + (size_t)(tr+i)*G_ + n0 + j3*4) = v;
    }
  }
}

// ---------------- Phase 2: GRU recurrence. One block per part, 192 threads (3 waves).
// Thread = one gate row (w_hh row in 64 VGPRs). h replicated lane-distributed per wave;
// dot via v_readlane broadcast (no LDS). One barrier/step via double-buffered hp exchange.
__global__ __launch_bounds__(192) void gru_kernel(
    const float* __restrict__ xp, const float* __restrict__ w_hh,
    const float* __restrict__ b_hh, float* __restrict__ hs,
    float* __restrict__ hstate, int t0, int tcLen)
{
  __shared__ float hpb[2][192];
  const int p = blockIdx.x;
  const int tid = threadIdx.x;
  const int lane = tid & 63;
  const int wv = tid >> 6;

  float w[64];
  {
    const float4* wr = (const float4*)(w_hh + ((size_t)p*G_ + tid)*H_);
    #pragma unroll
    for (int i=0;i<16;i++){ float4 v = wr[i]; w[4*i]=v.x; w[4*i+1]=v.y; w[4*i+2]=v.z; w[4*i+3]=v.w; }
  }
  const float bh = b_hh[p*G_ + tid];
  float h = 0.0f;
  if (t0 != 0) h = hstate[p*H_ + lane];

  const float* xrow = xp + (size_t)p*tcLen*G_;
  float xr_n = xrow[lane], xz_n = xrow[64+lane], xn_n = xrow[128+lane];
  float* hsrow = hs + ((size_t)p*T_ + (size_t)t0)*H_;

  int buf = 0;
  for (int tl=0; tl<tcLen; ++tl){
    float xr = xr_n, xz = xz_n, xn = xn_n;
    int tn = (tl+1 < tcLen) ? tl+1 : tl;
    const float* xnrow = xrow + (size_t)tn*G_;
    xr_n = xnrow[lane]; xz_n = xnrow[64+lane]; xn_n = xnrow[128+lane];

    float a0=0.f,a1=0.f,a2=0.f,a3=0.f;
    #pragma unroll
    for (int j=0;j<64;j+=4){
      float h0 = __int_as_float(__builtin_amdgcn_readlane(__float_as_int(h), j));
      float h1 = __int_as_float(__builtin_amdgcn_readlane(__float_as_int(h), j+1));
      float h2 = __int_as_float(__builtin_amdgcn_readlane(__float_as_int(h), j+2));
      float h3 = __int_as_float(__builtin_amdgcn_readlane(__float_as_int(h), j+3));
      a0 = fmaf(h0, w[j+0], a0);
      a1 = fmaf(h1, w[j+1], a1);
      a2 = fmaf(h2, w[j+2], a2);
      a3 = fmaf(h3, w[j+3], a3);
    }
    float hp = ((a0+a1)+(a2+a3)) + bh;
    hpb[buf][tid] = hp;
    __syncthreads();
    float hr = hpb[buf][lane], hz = hpb[buf][64+lane], hn = hpb[buf][128+lane];
    float r = sigmoidf_(xr + hr);
    float u = sigmoidf_(xz + hz);
    float n = tanhf_(xn + r*hn);
    h = (1.0f - u)*n + u*h;                 // identical across all 3 waves (same inputs)
    if (wv == 0) hsrow[(size_t)tl*H_ + lane] = h;
    buf ^= 1;
  }
  if (wv == 0) hstate[p*H_ + lane] = h;
}

// ---------------- Phase 3: fused 4-layer MLP. Block = (part, 64-t tile).
// Activations ping-pong in LDS (51 KB -> 3 blocks/CU). Weights read from global (L1 broadcast).
template<int K, int N, int NPT, bool RELU, bool TOGLOBAL>
__device__ __forceinline__ void layer_(
    const float* __restrict__ Xl, const float* __restrict__ Wg,
    const float* __restrict__ bg, float* Yl, float* outg, int tid)
{
  constexpr int NG = N / NPT;
  constexpr int XS = K + 4;
  constexpr int YS = N + 4;
  const int tg = tid & 15, ng = tid >> 4;
  if (ng < NG){
    const int tr = tg*4, n0 = ng*NPT;
    float acc[4][NPT];
    #pragma unroll
    for (int j=0;j<NPT;j++){
      float b = bg[n0+j];
      #pragma unroll
      for (int i=0;i<4;i++) acc[i][j] = b;
    }
    #pragma unroll 4
    for (int k=0;k<K;k+=4){
      float4 x4[4];
      #pragma unroll
      for (int i=0;i<4;i++) x4[i] = *(const float4*)(Xl + (tr+i)*XS + k);
      #pragma unroll
      for (int j=0;j<NPT;j++){
        float4 w4 = *(const float4*)(Wg + (size_t)(n0+j)*K + k);
        #pragma unroll
        for (int i=0;i<4;i++)
          acc[i][j] = fmaf(x4[i].x,w4.x, fmaf(x4[i].y,w4.y, fmaf(x4[i].z,w4.z, fmaf(x4[i].w,w4.w, acc[i][j]))));
      }
    }
    #pragma unroll
    for (int i=0;i<4;i++){
      #pragma unroll
      for (int j=0;j<NPT;j++){
        float v = acc[i][j];
        if (RELU) v = fmaxf(v, 0.0f);
        if (TOGLOBAL) outg[(size_t)(tr+i)*OUT_ + n0 + j] = v;
        else          Yl[(tr+i)*YS + n0 + j] = v;
      }
    }
  }
}

__global__ __launch_bounds__(256) void mlp_kernel(
    const float* __restrict__ hs,
    const float* __restrict__ w1, const float* __restrict__ b1,
    const float* __restrict__ w2, const float* __restrict__ b2,
    const float* __restrict__ w3, const float* __restrict__ b3,
    const float* __restrict__ w4, const float* __restrict__ b4,
    float* __restrict__ out)
{
  __shared__ float bufA[64*68];    // hs tile / a2
  __shared__ float bufB[64*132];   // a1 / a3
  const int p = blockIdx.y;
  const int t0 = blockIdx.x*64;
  const int tid = threadIdx.x;

  const float* hg = hs + ((size_t)p*T_ + (size_t)t0)*H_;
  #pragma unroll
  for (int i=0;i<4;i++){
    int idx = tid + i*256;
    int r = idx >> 4, c = idx & 15;
    *(float4*)(bufA + r*68 + c*4) = *(const float4*)(hg + (size_t)r*H_ + c*4);
  }
  __syncthreads();
  layer_<64,128,8,true,false>(bufA, w1 + (size_t)p*128*64, b1 + p*128, bufB, nullptr, tid);
  __syncthreads();
  layer_<128,64,4,true,false>(bufB, w2 + (size_t)p*64*128, b2 + p*64, bufA, nullptr, tid);
  __syncthreads();
  layer_<64,32,2,true,false>(bufA, w3 + (size_t)p*32*64, b3 + p*32, bufB, nullptr, tid);
  __syncthreads();
  float* og = out + ((size_t)p*T_ + (size_t)t0)*OUT_;
  layer_<32,24,2,false,true>(bufB, w4 + (size_t)p*24*32, b4 + p*24, nullptr, og, tid);
}

extern "C" void kernel_launch(void* const* d_in, const int* in_sizes, int n_in,
                              void* d_out, int out_size, void* d_ws, size_t ws_size,
                              hipStream_t stream)
{
  const float* z    = (const float*)d_in[0];
  const float* w_ih = (const float*)d_in[1];
  const float* w_hh = (const float*)d_in[2];
  const float* b_ih = (const float*)d_in[3];
  const float* b_hh = (const float*)d_in[4];
  const float* w1 = (const float*)d_in[5];
  const float* b1 = (const float*)d_in[6];
  const float* w2 = (const float*)d_in[7];
  const float* b2 = (const float*)d_in[8];
  const float* w3 = (const float*)d_in[9];
  const float* b3 = (const float*)d_in[10];
  const float* w4 = (const float*)d_in[11];
  const float* b4 = (const float*)d_in[12];
  float* out = (float*)d_out;

  // ws layout: [x_proj chunk | hs (full T) | h_state]. Pick largest T-chunk that fits.
  const size_t hsBytes = (size_t)P_*T_*H_*sizeof(float);     // 64 MB
  const size_t stBytes = (size_t)P_*H_*sizeof(float);        // 32 KB
  int tc = 64;
  for (int cand = T_; cand >= 64; cand >>= 1){
    size_t need = (size_t)P_*cand*G_*sizeof(float) + hsBytes + stBytes;
    if (need <= ws_size){ tc = cand; break; }
  }
  float* xp     = (float*)d_ws;
  float* hsbuf  = (float*)((char*)d_ws + (size_t)P_*tc*G_*sizeof(float));
  float* hstate = hsbuf + (size_t)P_*T_*H_;

  for (int t0 = 0; t0 < T_; t0 += tc){
    xproj_kernel<<<dim3(tc/64, P_), 256, 0, stream>>>(z, w_ih, b_ih, xp, t0, tc);
    gru_kernel<<<dim3(P_), 192, 0, stream>>>(xp, w_hh, b_hh, hsbuf, hstate, t0, tc);
  }
  mlp_kernel<<<dim3(T_/64, P_), 256, 0, stream>>>(hsbuf, w1,b1,w2,b2,w3,b3,w4,b4, out);
}

// Round 2
// 1614.903 us; speedup vs baseline: 1.0702x; 1.0702x over previous
//
#include <hip/hip_runtime.h>

#define P_ 128
#define T_ 2048
#define D_ 128
#define H_ 64
#define G_ 192
#define OUT_ 24

typedef float v2f __attribute__((ext_vector_type(2)));

__device__ __forceinline__ float sigmoidf_(float x){ return 1.0f/(1.0f + __expf(-x)); }
__device__ __forceinline__ float tanhf_(float x){
  float a = fabsf(x);
  float e = __expf(-2.0f*a);
  float t = (1.0f - e)/(1.0f + e);
  return copysignf(t, x);
}
__device__ __forceinline__ float rdlane_(float v, int l){
  return __int_as_float(__builtin_amdgcn_readlane(__float_as_int(v), l));
}

// ---------------- Phase 1: x_proj[p, tl, g] = sum_d z[p,t0+tl,d]*w_ih[p,g,d] + b_ih[p,g]
__global__ __launch_bounds__(256) void xproj_kernel(
    const float* __restrict__ z, const float* __restrict__ w_ih,
    const float* __restrict__ b_ih, float* __restrict__ xp,
    int t0, int tcLen)
{
  __shared__ float zl[64*132];
  const int p = blockIdx.y;
  const int tBase = blockIdx.x*64;
  const int tid = threadIdx.x;
  const float* zg = z + ((size_t)p*T_ + (size_t)(t0 + tBase))*D_;
  #pragma unroll
  for (int i=0;i<8;i++){
    int idx = tid + i*256;
    int r = idx >> 5, c = idx & 31;
    *(float4*)(zl + r*132 + c*4) = *(const float4*)(zg + (size_t)r*D_ + c*4);
  }
  __syncthreads();

  const int tg = tid & 15, ng = tid >> 4;
  const int n0 = ng*12, tr = tg*4;
  const float* wg = w_ih + (size_t)p*G_*D_;
  float acc[4][12];
  #pragma unroll
  for (int j=0;j<12;j++){
    float b = b_ih[p*G_ + n0 + j];
    #pragma unroll
    for (int i=0;i<4;i++) acc[i][j] = b;
  }
  #pragma unroll 4
  for (int k=0;k<D_;k+=4){
    float4 x4[4];
    #pragma unroll
    for (int i=0;i<4;i++) x4[i] = *(const float4*)(zl + (tr+i)*132 + k);
    #pragma unroll
    for (int j=0;j<12;j++){
      float4 w4 = *(const float4*)(wg + (size_t)(n0+j)*D_ + k);
      #pragma unroll
      for (int i=0;i<4;i++)
        acc[i][j] = fmaf(x4[i].x,w4.x, fmaf(x4[i].y,w4.y, fmaf(x4[i].z,w4.z, fmaf(x4[i].w,w4.w, acc[i][j]))));
    }
  }
  float* orow = xp + ((size_t)p*tcLen + tBase)*G_;
  #pragma unroll
  for (int i=0;i<4;i++){
    #pragma unroll
    for (int j3=0;j3<3;j3++){
      float4 v = make_float4(acc[i][j3*4+0],acc[i][j3*4+1],acc[i][j3*4+2],acc[i][j3*4+3]);
      *(float4*)(orow + (size_t)(tr+i)*G_ + n0 + j3*4) = v;
    }
  }
}

// ---------------- Phase 2: GRU recurrence. ONE WAVE per part, no LDS, no barriers.
// Lane l owns gate rows r_l, z_l, n_l (192 floats in VGPRs). h broadcast via
// v_readlane (shared across the 3 gates); dot as float2 pairs -> v_pk_fma_f32.
__global__ __launch_bounds__(64, 1) void gru_kernel(
    const float* __restrict__ xp, const float* __restrict__ w_hh,
    const float* __restrict__ b_hh, float* __restrict__ hs,
    float* __restrict__ hstate, int t0, int tcLen)
{
  const int p = blockIdx.x;
  const int l = threadIdx.x;            // lane, 0..63

  // Load the three gate rows for this lane into VGPR pairs.
  v2f wr2[32], wz2[32], wn2[32];
  {
    const float* Wr = w_hh + ((size_t)p*G_ + l)*H_;
    const float* Wz = Wr + (size_t)64*H_;
    const float* Wn = Wr + (size_t)128*H_;
    #pragma unroll
    for (int i=0;i<16;i++){
      float4 a = *(const float4*)(Wr + 4*i);
      float4 b = *(const float4*)(Wz + 4*i);
      float4 c = *(const float4*)(Wn + 4*i);
      wr2[2*i]   = v2f{a.x, a.y}; wr2[2*i+1] = v2f{a.z, a.w};
      wz2[2*i]   = v2f{b.x, b.y}; wz2[2*i+1] = v2f{b.z, b.w};
      wn2[2*i]   = v2f{c.x, c.y}; wn2[2*i+1] = v2f{c.z, c.w};
    }
  }
  const float br = b_hh[p*G_ + l];
  const float bz = b_hh[p*G_ + 64 + l];
  const float bn = b_hh[p*G_ + 128 + l];

  float h = 0.0f;
  if (t0 != 0) h = hstate[p*H_ + l];

  const float* xrow = xp + (size_t)p*tcLen*G_;
  float xr_n = xrow[l], xz_n = xrow[64+l], xn_n = xrow[128+l];
  float* hsrow = hs + ((size_t)p*T_ + (size_t)t0)*H_;

  for (int tl=0; tl<tcLen; ++tl){
    float xr = xr_n, xz = xz_n, xn = xn_n;
    int tn = (tl+1 < tcLen) ? tl+1 : tl;
    const float* xnrow = xrow + (size_t)tn*G_;
    xr_n = xnrow[l]; xz_n = xnrow[64+l]; xn_n = xnrow[128+l];

    v2f ar = v2f{br, 0.0f};
    v2f az = v2f{bz, 0.0f};
    v2f an = v2f{bn, 0.0f};
    #pragma unroll
    for (int j=0;j<32;j++){
      float h0 = rdlane_(h, 2*j);
      float h1 = rdlane_(h, 2*j+1);
      v2f h2 = v2f{h0, h1};
      ar = __builtin_elementwise_fma(wr2[j], h2, ar);
      az = __builtin_elementwise_fma(wz2[j], h2, az);
      an = __builtin_elementwise_fma(wn2[j], h2, an);
    }
    float hr = ar.x + ar.y;
    float hz = az.x + az.y;
    float hn = an.x + an.y;

    float r = sigmoidf_(xr + hr);
    float u = sigmoidf_(xz + hz);
    float n = tanhf_(xn + r*hn);
    h = (1.0f - u)*n + u*h;
    hsrow[(size_t)tl*H_ + l] = h;
  }
  hstate[p*H_ + l] = h;
}

// ---------------- Phase 3: fused 4-layer MLP.
template<int K, int N, int NPT, bool RELU, bool TOGLOBAL>
__device__ __forceinline__ void layer_(
    const float* __restrict__ Xl, const float* __restrict__ Wg,
    const float* __restrict__ bg, float* Yl, float* outg, int tid)
{
  constexpr int NG = N / NPT;
  constexpr int XS = K + 4;
  constexpr int YS = N + 4;
  const int tg = tid & 15, ng = tid >> 4;
  if (ng < NG){
    const int tr = tg*4, n0 = ng*NPT;
    float acc[4][NPT];
    #pragma unroll
    for (int j=0;j<NPT;j++){
      float b = bg[n0+j];
      #pragma unroll
      for (int i=0;i<4;i++) acc[i][j] = b;
    }
    #pragma unroll 4
    for (int k=0;k<K;k+=4){
      float4 x4[4];
      #pragma unroll
      for (int i=0;i<4;i++) x4[i] = *(const float4*)(Xl + (tr+i)*XS + k);
      #pragma unroll
      for (int j=0;j<NPT;j++){
        float4 w4 = *(const float4*)(Wg + (size_t)(n0+j)*K + k);
        #pragma unroll
        for (int i=0;i<4;i++)
          acc[i][j] = fmaf(x4[i].x,w4.x, fmaf(x4[i].y,w4.y, fmaf(x4[i].z,w4.z, fmaf(x4[i].w,w4.w, acc[i][j]))));
      }
    }
    #pragma unroll
    for (int i=0;i<4;i++){
      #pragma unroll
      for (int j=0;j<NPT;j++){
        float v = acc[i][j];
        if (RELU) v = fmaxf(v, 0.0f);
        if (TOGLOBAL) outg[(size_t)(tr+i)*OUT_ + n0 + j] = v;
        else          Yl[(tr+i)*YS + n0 + j] = v;
      }
    }
  }
}

__global__ __launch_bounds__(256) void mlp_kernel(
    const float* __restrict__ hs,
    const float* __restrict__ w1, const float* __restrict__ b1,
    const float* __restrict__ w2, const float* __restrict__ b2,
    const float* __restrict__ w3, const float* __restrict__ b3,
    const float* __restrict__ w4, const float* __restrict__ b4,
    float* __restrict__ out)
{
  __shared__ float bufA[64*68];
  __shared__ float bufB[64*132];
  const int p = blockIdx.y;
  const int t0 = blockIdx.x*64;
  const int tid = threadIdx.x;

  const float* hg = hs + ((size_t)p*T_ + (size_t)t0)*H_;
  #pragma unroll
  for (int i=0;i<4;i++){
    int idx = tid + i*256;
    int r = idx >> 4, c = idx & 15;
    *(float4*)(bufA + r*68 + c*4) = *(const float4*)(hg + (size_t)r*H_ + c*4);
  }
  __syncthreads();
  layer_<64,128,8,true,false>(bufA, w1 + (size_t)p*128*64, b1 + p*128, bufB, nullptr, tid);
  __syncthreads();
  layer_<128,64,4,true,false>(bufB, w2 + (size_t)p*64*128, b2 + p*64, bufA, nullptr, tid);
  __syncthreads();
  layer_<64,32,2,true,false>(bufA, w3 + (size_t)p*32*64, b3 + p*32, bufB, nullptr, tid);
  __syncthreads();
  float* og = out + ((size_t)p*T_ + (size_t)t0)*OUT_;
  layer_<32,24,2,false,true>(bufB, w4 + (size_t)p*24*32, b4 + p*24, nullptr, og, tid);
}

extern "C" void kernel_launch(void* const* d_in, const int* in_sizes, int n_in,
                              void* d_out, int out_size, void* d_ws, size_t ws_size,
                              hipStream_t stream)
{
  const float* z    = (const float*)d_in[0];
  const float* w_ih = (const float*)d_in[1];
  const float* w_hh = (const float*)d_in[2];
  const float* b_ih = (const float*)d_in[3];
  const float* b_hh = (const float*)d_in[4];
  const float* w1 = (const float*)d_in[5];
  const float* b1 = (const float*)d_in[6];
  const float* w2 = (const float*)d_in[7];
  const float* b2 = (const float*)d_in[8];
  const float* w3 = (const float*)d_in[9];
  const float* b3 = (const float*)d_in[10];
  const float* w4 = (const float*)d_in[11];
  const float* b4 = (const float*)d_in[12];
  float* out = (float*)d_out;

  const size_t hsBytes = (size_t)P_*T_*H_*sizeof(float);
  const size_t stBytes = (size_t)P_*H_*sizeof(float);
  int tc = 64;
  for (int cand = T_; cand >= 64; cand >>= 1){
    size_t need = (size_t)P_*cand*G_*sizeof(float) + hsBytes + stBytes;
    if (need <= ws_size){ tc = cand; break; }
  }
  float* xp     = (float*)d_ws;
  float* hsbuf  = (float*)((char*)d_ws + (size_t)P_*tc*G_*sizeof(float));
  float* hstate = hsbuf + (size_t)P_*T_*H_;

  for (int t0 = 0; t0 < T_; t0 += tc){
    xproj_kernel<<<dim3(tc/64, P_), 256, 0, stream>>>(z, w_ih, b_ih, xp, t0, tc);
    gru_kernel<<<dim3(P_), 64, 0, stream>>>(xp, w_hh, b_hh, hsbuf, hstate, t0, tc);
  }
  mlp_kernel<<<dim3(T_/64, P_), 256, 0, stream>>>(hsbuf, w1,b1,w2,b2,w3,b3,w4,b4, out);
}